// Round 8
// baseline (1999.128 us; speedup 1.0000x reference)
//
#include <hip/hip_runtime.h>
#include <hip/hip_bf16.h>

#define T_SEQ  180
#define LATENT 128
#define HIDDEN 256

typedef __attribute__((ext_vector_type(8))) short  short8;   // 8 x bf16 (4 VGPRs)
typedef __attribute__((ext_vector_type(4))) float  floatx4;  // f32 MFMA acc
typedef __attribute__((ext_vector_type(4))) int    intx4;    // i8 frag / i32 acc
typedef __attribute__((ext_vector_type(2))) float  float2v;  // packed f32 (v_pk_*)

#define LOG2E 1.4426950408889634f

// ---- d_ws layout (BYTES) ----
#define WQ_OFF    0        // w_hh i8 frags: ((w*6+sub)*4+kc)*1024, 192 KB
#define FCW_OFF   196608   // fc_w bf16 frags (r9/r13 layout), 64 KB
#define SCW_OFF   262144   // w_hh row scales: float[768]
#define OUTW_OFF  265216   // out_w i8 frags: [slice4][lane64][16B] = 4096 B
#define SWOUT_OFF 269312   // out_w row scales: float[2]

// ---- dynamic LDS layout (bytes) ----
// r27: HALF-SIZE BLOCK (16 rows). h ping-pong: 2 x 16 rows x 272 B;
// obuf double-buffered by parity: [pp2][sl4][16][2] int32 = 1 KB.
// Total 9728 B -> TWO blocks fit per CU.
#define H8_STRIDE  272
#define H8B_OFF    4352
#define OBUF_OFF   8704
#define OBUF_HALF  128     // ints per parity half
#define SMEM_BYTES 9728

__device__ __forceinline__ unsigned short f2bf(float f) {
    unsigned int u = __float_as_uint(f);
    u += 0x7fffu + ((u >> 16) & 1u);      // round-to-nearest-even
    return (unsigned short)(u >> 16);
}

// Per-output-unit scales: one wave per row j of w_hh.
__global__ void pack_scales(const float* __restrict__ whh, float* __restrict__ scales) {
    int wid  = blockIdx.x * 4 + (threadIdx.x >> 6);   // 0..767
    int lane = threadIdx.x & 63;
    const float* src = whh + (size_t)wid * 256 + lane * 4;
    float m = 0.0f;
#pragma unroll
    for (int j = 0; j < 4; ++j) m = fmaxf(m, fabsf(src[j]));
#pragma unroll
    for (int d = 1; d < 64; d <<= 1) m = fmaxf(m, __shfl_xor(m, d, 64));
    if (lane == 0) scales[wid] = m;
}

// Pack w_hh [768,256] fp32 -> i8 16x16x64 B-frags (r13-verified layout).
__global__ void pack_whh_i8(const float* __restrict__ whh, const float* __restrict__ scales,
                            signed char* __restrict__ dst) {
    int tid  = blockIdx.x * blockDim.x + threadIdx.x;  // 12288 threads
    int lane = tid & 63;
    int frag = tid >> 6;                               // 0..191
    int kc   = frag & 3;
    int sub  = (frag >> 2) % 6;
    int w    = frag / 24;
    int g = sub >> 1, cs = sub & 1;
    int col  = w * 32 + cs * 16 + (lane & 15);
    int jout = g * 256 + col;
    int k0   = kc * 64 + ((lane >> 4) << 4);
    const float* src = whh + (size_t)jout * 256 + k0;
    float inv = 127.0f / scales[jout];
    signed char q[16];
#pragma unroll
    for (int j = 0; j < 16; ++j) {
        float v = __builtin_rintf(src[j] * inv);
        v = fminf(fmaxf(v, -127.0f), 127.0f);
        q[j] = (signed char)(int)v;
    }
    *(intx4*)(dst + (size_t)frag * 1024 + lane * 16) = *(intx4*)q;
}

// Pack fc_w [256,128] fp32 -> bf16 16x16x32 B-frags (r9 layout).
__global__ void pack_fcw(const float* __restrict__ fcw, unsigned short* __restrict__ dst) {
    int tid  = blockIdx.x * blockDim.x + threadIdx.x;  // 4096 threads
    int lane = tid & 63;
    int frag = tid >> 6;                               // 0..63
    int kc   = frag & 3;
    int cs   = (frag >> 2) & 1;
    int w    = frag >> 3;
    int col  = w * 32 + cs * 16 + (lane & 15);
    int k0   = kc * 32 + ((lane >> 4) << 3);
    const float* src = fcw + col * 128 + k0;
    unsigned int u[4];
#pragma unroll
    for (int j = 0; j < 4; ++j)
        u[j] = (unsigned int)f2bf(src[2 * j]) | ((unsigned int)f2bf(src[2 * j + 1]) << 16);
    *(uint4*)(dst + frag * 512 + lane * 8) = make_uint4(u[0], u[1], u[2], u[3]);
}

// Quantize out_w [2,256] -> i8 proj B-frags [slice4][lane][16B] + row scales.
__global__ void pack_outw_i8(const float* __restrict__ out_w,
                             signed char* __restrict__ dst, float* __restrict__ swout) {
    __shared__ float sw[2];
    int tid = threadIdx.x;
    if (tid < 128) {
        int o = tid >> 6, lane = tid & 63;
        const float* src = out_w + o * 256 + lane * 4;
        float m = 0.0f;
#pragma unroll
        for (int j = 0; j < 4; ++j) m = fmaxf(m, fabsf(src[j]));
#pragma unroll
        for (int d = 1; d < 64; d <<= 1) m = fmaxf(m, __shfl_xor(m, d, 64));
        if (lane == 0) { sw[o] = m; swout[o] = m; }
    }
    __syncthreads();
    int sl = tid >> 6, lane = tid & 63;
    int n  = lane & 15;
    int k0 = sl * 64 + ((lane >> 4) << 4);
    signed char q[16];
#pragma unroll
    for (int j = 0; j < 16; ++j) {
        float v = 0.0f;
        if (n < 2) {
            v = __builtin_rintf(out_w[n * 256 + k0 + j] * (127.0f / sw[n]));
            v = fminf(fmaxf(v, -127.0f), 127.0f);
        }
        q[j] = (signed char)(int)v;
    }
    *(intx4*)(dst + sl * 1024 + lane * 16) = *(intx4*)q;
}

// Persistent GRU r27: TWO BLOCKS PER CU (occupancy doubling).
// r19-r26 all ran 1 block/CU at 4 waves/SIMD (Occupancy 46%) -- every
// schedule permutation inside that envelope landed 440-460us with ~20-30%
// of issue slots idle on latency (ds_read->MFMA, serial exp2->rcp chains,
// barrier re-entry) that 4 barrier-locked identical waves cannot hide.
// r27 halves the block (16 batch rows, one 16-row tile per wave):
//  - LDS 19.5KB -> 9.7KB, acc/hm halve -> VGPR fits 64
//  - __launch_bounds__(1024, 8): 8 waves/SIMD = 2 independent blocks/CU
//  - the two blocks drift out of phase naturally: block A's HUPD/trans
//    overlaps block B's MFMA on the same SIMD (real desync, unlike r26)
// Step: monolithic 1-barrier, parity obuf, mid-step flush, packed HUPD,
// zero4 C-operand, setprio(1) around MFMA clusters (cross-block diversity).
__global__ __launch_bounds__(1024, 8) void gru_main(
    const float* __restrict__ z,
    const float* __restrict__ fc_b,
    const float* __restrict__ b_ih,
    const float* __restrict__ b_hh,
    const float* __restrict__ out_b,
    const unsigned char* __restrict__ ws,
    float* __restrict__ out)
{
    extern __shared__ unsigned char smem[];
    signed char* h8a   = (signed char*)smem;                 // buf parity 0
    signed char* h8b   = (signed char*)(smem + H8B_OFF);     // buf parity 1
    int*         obufI = (int*)(smem + OBUF_OFF);            // [pp2][sl4][16][2]

    const int tid  = threadIdx.x;
    const int lane = tid & 63;
    const int wv   = tid >> 6;       // 0..15
    const int cg   = wv;             // 16-col group owned by this wave
    const int l15  = lane & 15;
    const int qd   = lane >> 4;
    const int sl   = wv & 3;         // proj 64-col k-slice (waves 0-3)
    const int rb   = blockIdx.x * 16;

    const intx4 zero4 = (intx4){0, 0, 0, 0};   // persistent MFMA C-init

    // ---- ALL 3 gates' i8 weight frags into registers (12 frags = 48 VGPRs) ----
    intx4 wq[12];
#pragma unroll
    for (int g = 0; g < 3; ++g)
#pragma unroll
        for (int kc = 0; kc < 4; ++kc)
            wq[g * 4 + kc] = *(const intx4*)(ws + WQ_OFF
                + (size_t)((((cg >> 1) * 6 + g * 2 + (cg & 1)) * 4 + kc)) * 1024 + lane * 16);

    // ---- proj B-frag (i8; used on waves 0-3) + per-lane constants ----
    intx4 bproj = *(const intx4*)(ws + OUTW_OFF + sl * 1024 + lane * 16);
    const float* swout = (const float*)(ws + SWOUT_OFF);
    float pscF = swout[lane & 1] * (1.0f / 16129.0f);   // flush scale (o = lane&1)

    const float* scales = (const float*)(ws + SCW_OFF);
    float fcbE2;
    float2v nscqr2, ncbr2, nscqz2, ncbz2, scqn2, bhn2, bin2;
    {
        int col = cg * 16 + l15;
        float ncbrE  = -(b_ih[col]       + b_hh[col])       * LOG2E;
        float ncbzE  = -(b_ih[256 + col] + b_hh[256 + col]) * LOG2E;
        float binE2  = b_ih[512 + col] * (2.0f * LOG2E);
        float bhnE2  = b_hh[512 + col] * (2.0f * LOG2E);
        fcbE2  = fc_b[col] * (2.0f * LOG2E);
        float nscqrE = -scales[col]       * (LOG2E / 16129.0f);
        float nscqzE = -scales[256 + col] * (LOG2E / 16129.0f);
        float scqnE2 = scales[512 + col] * (2.0f * LOG2E / 16129.0f);
        nscqr2 = (float2v){nscqrE, nscqrE};  ncbr2 = (float2v){ncbrE, ncbrE};
        nscqz2 = (float2v){nscqzE, nscqzE};  ncbz2 = (float2v){ncbzE, ncbzE};
        scqn2  = (float2v){scqnE2, scqnE2};  bhn2  = (float2v){bhnE2, bhnE2};
        bin2   = (float2v){binE2, binE2};
    }
    const float2v m254 = (float2v){-254.0f, -254.0f};
    const float2v p127 = (float2v){127.0f, 127.0f};
    float ob = out_b[lane & 1];

    // LDS byte offsets (one base reg + compile-time imms each)
    const int rdOff = l15 * H8_STRIDE + qd * 16;                    // A-frag reads
    const int pjOff = l15 * H8_STRIDE + sl * 64 + qd * 16;          // proj read
    const int wrOff = (qd * 4) * H8_STRIDE + cg * 16 + l15;         // h stores

    // flush bookkeeping: wave 8, lanes 0-31 (16 rows x 2 outs)
    const int rlW = (lane >> 1) & 15;
    const int o8  = lane & 1;
    const int fbase = rlW * 2 + o8;                                 // within a half
    float* opW8 = out + (size_t)(rb + rlW) * (T_SEQ * 2) + o8;      // -> out idx 0

    // ---- h0 = tanh(fc(z)) kept x127: bf16 MFMA, A-frags direct from global ----
    floatx4 a0f = (floatx4){0.f, 0.f, 0.f, 0.f};
#pragma unroll
    for (int kc = 0; kc < 4; ++kc) {
        short8 bfr = *(const short8*)(ws + FCW_OFF + (size_t)(cg * 4 + kc) * 1024 + lane * 16);
        const float* zp = z + (size_t)(rb + l15) * LATENT + kc * 32 + qd * 8;
        short8 afr;
#pragma unroll
        for (int j = 0; j < 8; ++j) afr[j] = (short)f2bf(zp[j]);
        a0f = __builtin_amdgcn_mfma_f32_16x16x32_bf16(afr, bfr, a0f, 0, 0, 0);
    }

    float2v hm2[2];   // 127-scaled hidden state, packed in r-pairs
#pragma unroll
    for (int r = 0; r < 4; ++r) {
        float u = __builtin_amdgcn_rcpf(1.0f + __builtin_amdgcn_exp2f(
                      __builtin_fmaf(a0f[r], 2.0f * LOG2E, fcbE2)));
        float h = __builtin_fmaf(-254.0f, u, 127.0f);   // 127*tanh(.)
        hm2[r >> 1][r & 1] = h;
        h8a[wrOff + r * H8_STRIDE] =
            (signed char)__float_as_uint(h + 12582912.0f);   // RNE int8 low byte
    }
    __syncthreads();

    intx4 acc[3];

#define MFI8(A, B, C) __builtin_amdgcn_mfma_i32_16x16x64_i8((A), (B), (C), 0, 0, 0)

    // one PACKED h-update pair (rows 2P, 2P+1): acc -> gates -> h -> i8 stores
#define HUPD_PAIR(P, WP)                                                          \
    {                                                                             \
        float2v arv, azv, anv;                                                    \
        arv[0] = (float)acc[0][2*(P)];   arv[1] = (float)acc[0][2*(P)+1];         \
        azv[0] = (float)acc[1][2*(P)];   azv[1] = (float)acc[1][2*(P)+1];         \
        anv[0] = (float)acc[2][2*(P)];   anv[1] = (float)acc[2][2*(P)+1];         \
        float2v yr = __builtin_elementwise_fma(arv, nscqr2, ncbr2);               \
        float2v yz = __builtin_elementwise_fma(azv, nscqz2, ncbz2);               \
        float2v Ar, Az;                                                           \
        Ar[0] = __builtin_amdgcn_exp2f(yr[0]); Ar[1] = __builtin_amdgcn_exp2f(yr[1]); \
        Az[0] = __builtin_amdgcn_exp2f(yz[0]); Az[1] = __builtin_amdgcn_exp2f(yz[1]); \
        float2v dr = Ar + 1.0f, dz = Az + 1.0f;                                   \
        float2v pr = dr * dz;                                                     \
        float2v q_;                                                               \
        q_[0] = __builtin_amdgcn_rcpf(pr[0]); q_[1] = __builtin_amdgcn_rcpf(pr[1]); \
        float2v gr = q_ * dz, gz = q_ * dr;                                       \
        float2v xn2 = __builtin_elementwise_fma(anv, scqn2, bhn2);                \
        float2v tt  = __builtin_elementwise_fma(gr, xn2, bin2);                   \
        float2v Ee, uu;                                                           \
        Ee[0] = __builtin_amdgcn_exp2f(tt[0]); Ee[1] = __builtin_amdgcn_exp2f(tt[1]); \
        Ee = Ee + 1.0f;                                                           \
        uu[0] = __builtin_amdgcn_rcpf(Ee[0]); uu[1] = __builtin_amdgcn_rcpf(Ee[1]); \
        float2v gn = __builtin_elementwise_fma(m254, uu, p127);                   \
        float2v hv = hm2[P];                                                      \
        float2v hn = __builtin_elementwise_fma(gz, hv - gn, gn);                  \
        hm2[P] = hn;                                                              \
        float2v hb = hn + 12582912.0f;                                            \
        (WP)[(2*(P))   * H8_STRIDE] = (signed char)__float_as_uint(hb[0]);        \
        (WP)[(2*(P)+1) * H8_STRIDE] = (signed char)__float_as_uint(hb[1]);        \
    }

#define FLUSH(OBR) {                                                              \
        int s_ = (OBR)[fbase] + (OBR)[fbase + 32]                                 \
               + (OBR)[fbase + 64] + (OBR)[fbase + 96];                           \
        *opW8 = __builtin_fmaf((float)s_, pscF, ob);                              \
        opW8 += 2;                                                                \
    }
#define STASH(OBW) {                                                              \
        _Pragma("unroll")                                                         \
        for (int r = 0; r < 4; ++r)                                               \
            (OBW)[sl * 32 + (qd * 4 + r) * 2 + l15] = pj[r];                      \
    }

    // ---- one monolithic GRU step, ONE barrier ----
#define GRU_STEP(H8P, H8N, OBR, OBW, DO_STASH, DO_FLUSH)                          \
    {                                                                             \
        const signed char* rp = (H8P) + rdOff;                                    \
        signed char*       wp = (H8N) + wrOff;                                    \
        intx4 pj;                                                                 \
        if (DO_STASH && wv < 4) {                                                 \
            intx4 a8p = *(const intx4*)((H8P) + pjOff);                           \
            pj = MFI8(a8p, bproj, zero4);                                         \
        }                                                                         \
        __builtin_amdgcn_s_setprio(1);                                            \
        intx4 a8 = *(const intx4*)(rp);                                           \
        acc[0] = MFI8(a8, wq[0], zero4);                                          \
        acc[1] = MFI8(a8, wq[4], zero4);                                          \
        acc[2] = MFI8(a8, wq[8], zero4);                                          \
        a8 = *(const intx4*)(rp + 64);                                            \
        acc[0] = MFI8(a8, wq[1], acc[0]);                                         \
        acc[1] = MFI8(a8, wq[5], acc[1]);                                         \
        acc[2] = MFI8(a8, wq[9], acc[2]);                                         \
        a8 = *(const intx4*)(rp + 128);                                           \
        acc[0] = MFI8(a8, wq[2], acc[0]);                                         \
        acc[1] = MFI8(a8, wq[6], acc[1]);                                         \
        acc[2] = MFI8(a8, wq[10], acc[2]);                                        \
        a8 = *(const intx4*)(rp + 192);                                           \
        acc[0] = MFI8(a8, wq[3], acc[0]);                                         \
        acc[1] = MFI8(a8, wq[7], acc[1]);                                         \
        acc[2] = MFI8(a8, wq[11], acc[2]);                                        \
        __builtin_amdgcn_s_setprio(0);                                            \
        if (DO_FLUSH && wv == 8 && lane < 32) { FLUSH(OBR) }                      \
        HUPD_PAIR(0, wp)                                                          \
        HUPD_PAIR(1, wp)                                                          \
        if (DO_STASH && wv < 4 && l15 < 2) { STASH(OBW) }                         \
        __syncthreads();                                                          \
    }

    int* ob0 = obufI;               // parity-0 half
    int* ob1 = obufI + OBUF_HALF;   // parity-1 half

    // ---- prologue: t=0,1 peeled ----
    GRU_STEP(h8a, h8b, ob1, ob0, 0, 0)   // t=0 (p=0): no stash, no flush
    GRU_STEP(h8b, h8a, ob0, ob1, 1, 0)   // t=1 (p=1): stash proj(s_1)->obuf[1]

    // ---- steady state: t = 2..179, 89 parity pairs ----
#pragma unroll 1
    for (int t2 = 0; t2 < 89; ++t2) {
        GRU_STEP(h8a, h8b, ob1, ob0, 1, 1)   // even t: flush obuf[1] (out t-2)
        GRU_STEP(h8b, h8a, ob0, ob1, 1, 1)   // odd t : flush obuf[0]
    }

    // ---- epilogue ----
    // last step t=179 (p=1): stashed obuf[1] (out 178); h(180) in h8a.
    if (wv < 4) {          // proj(s_180) -> stash obuf[0]
        intx4 a8p = *(const intx4*)(h8a + pjOff);
        intx4 pj = MFI8(a8p, bproj, zero4);
        if (l15 < 2)
#pragma unroll
            for (int r = 0; r < 4; ++r)
                ob0[sl * 32 + (qd * 4 + r) * 2 + l15] = pj[r];
    }
    if (wv == 8 && lane < 32) {   // flush obuf[1] -> out idx 178
        int s_ = ob1[fbase] + ob1[fbase + 32] + ob1[fbase + 64] + ob1[fbase + 96];
        *opW8 = __builtin_fmaf((float)s_, pscF, ob);
        opW8 += 2;
    }
    __syncthreads();
    if (wv == 8 && lane < 32) {   // flush obuf[0] -> out idx 179
        int s_ = ob0[fbase] + ob0[fbase + 32] + ob0[fbase + 64] + ob0[fbase + 96];
        *opW8 = __builtin_fmaf((float)s_, pscF, ob);
    }
#undef GRU_STEP
#undef STASH
#undef FLUSH
#undef HUPD_PAIR
#undef MFI8
}

extern "C" void kernel_launch(void* const* d_in, const int* in_sizes, int n_in,
                              void* d_out, int out_size, void* d_ws, size_t ws_size,
                              hipStream_t stream) {
    const float* z     = (const float*)d_in[0];
    const float* fc_w  = (const float*)d_in[1];
    const float* fc_b  = (const float*)d_in[2];
    // d_in[3] = w_ih : unused (GRU input is all-zeros, gi = b_ih)
    const float* b_ih  = (const float*)d_in[4];
    const float* w_hh  = (const float*)d_in[5];
    const float* b_hh  = (const float*)d_in[6];
    const float* out_w = (const float*)d_in[7];
    const float* out_b = (const float*)d_in[8];
    float* out = (float*)d_out;
    unsigned char* ws = (unsigned char*)d_ws;   // needs 269,320 B

    hipFuncSetAttribute((const void*)gru_main,
                        hipFuncAttributeMaxDynamicSharedMemorySize, SMEM_BYTES);

    pack_scales<<<192, 256, 0, stream>>>(w_hh, (float*)(ws + SCW_OFF));
    pack_whh_i8<<<48, 256, 0, stream>>>(w_hh, (const float*)(ws + SCW_OFF),
                                        (signed char*)(ws + WQ_OFF));
    pack_fcw<<<16, 256, 0, stream>>>(fc_w, (unsigned short*)(ws + FCW_OFF));
    pack_outw_i8<<<1, 256, 0, stream>>>(out_w, (signed char*)(ws + OUTW_OFF),
                                        (float*)(ws + SWOUT_OFF));
    gru_main<<<512, 1024, SMEM_BYTES, stream>>>(z, fc_b, b_ih, b_hh, out_b, ws, out);
}

// Round 9
// 474.585 us; speedup vs baseline: 4.2124x; 4.2124x over previous
//
#include <hip/hip_runtime.h>
#include <hip/hip_bf16.h>

#define T_SEQ  180
#define LATENT 128
#define HIDDEN 256

typedef __attribute__((ext_vector_type(8))) short  short8;   // 8 x bf16 (4 VGPRs)
typedef __attribute__((ext_vector_type(4))) float  floatx4;  // f32 MFMA acc
typedef __attribute__((ext_vector_type(4))) int    intx4;    // i8 frag / i32 acc
typedef __attribute__((ext_vector_type(2))) float  float2v;  // packed f32 (v_pk_*)

#define LOG2E 1.4426950408889634f

// ---- d_ws layout (BYTES) ----
#define WQ_OFF    0        // w_hh i8 frags: ((w*6+sub)*4+kc)*1024, 192 KB
#define FCW_OFF   196608   // fc_w bf16 frags (r9/r13 layout), 64 KB
#define SCW_OFF   262144   // w_hh row scales: float[768]
#define OUTW_OFF  265216   // out_w i8 frags: [slice4][lane64][16B] = 4096 B
#define SWOUT_OFF 269312   // out_w row scales: float[2]

// ---- dynamic LDS layout (bytes) ----
// h ping-pong: 2 x 32 rows x 272 B; obuf single [rh2][sl4][16][2] int32
#define H8_STRIDE  272
#define H8B_OFF    8704
#define OBUF_OFF   17408
#define SMEM_BYTES 18432

__device__ __forceinline__ unsigned short f2bf(float f) {
    unsigned int u = __float_as_uint(f);
    u += 0x7fffu + ((u >> 16) & 1u);      // round-to-nearest-even
    return (unsigned short)(u >> 16);
}

// Per-output-unit scales: one wave per row j of w_hh.
__global__ void pack_scales(const float* __restrict__ whh, float* __restrict__ scales) {
    int wid  = blockIdx.x * 4 + (threadIdx.x >> 6);   // 0..767
    int lane = threadIdx.x & 63;
    const float* src = whh + (size_t)wid * 256 + lane * 4;
    float m = 0.0f;
#pragma unroll
    for (int j = 0; j < 4; ++j) m = fmaxf(m, fabsf(src[j]));
#pragma unroll
    for (int d = 1; d < 64; d <<= 1) m = fmaxf(m, __shfl_xor(m, d, 64));
    if (lane == 0) scales[wid] = m;
}

// Pack w_hh [768,256] fp32 -> i8 16x16x64 B-frags (r13-verified layout).
__global__ void pack_whh_i8(const float* __restrict__ whh, const float* __restrict__ scales,
                            signed char* __restrict__ dst) {
    int tid  = blockIdx.x * blockDim.x + threadIdx.x;  // 12288 threads
    int lane = tid & 63;
    int frag = tid >> 6;                               // 0..191
    int kc   = frag & 3;
    int sub  = (frag >> 2) % 6;
    int w    = frag / 24;
    int g = sub >> 1, cs = sub & 1;
    int col  = w * 32 + cs * 16 + (lane & 15);
    int jout = g * 256 + col;
    int k0   = kc * 64 + ((lane >> 4) << 4);
    const float* src = whh + (size_t)jout * 256 + k0;
    float inv = 127.0f / scales[jout];
    signed char q[16];
#pragma unroll
    for (int j = 0; j < 16; ++j) {
        float v = __builtin_rintf(src[j] * inv);
        v = fminf(fmaxf(v, -127.0f), 127.0f);
        q[j] = (signed char)(int)v;
    }
    *(intx4*)(dst + (size_t)frag * 1024 + lane * 16) = *(intx4*)q;
}

// Pack fc_w [256,128] fp32 -> bf16 16x16x32 B-frags (r9 layout).
__global__ void pack_fcw(const float* __restrict__ fcw, unsigned short* __restrict__ dst) {
    int tid  = blockIdx.x * blockDim.x + threadIdx.x;  // 4096 threads
    int lane = tid & 63;
    int frag = tid >> 6;                               // 0..63
    int kc   = frag & 3;
    int cs   = (frag >> 2) & 1;
    int w    = frag >> 3;
    int col  = w * 32 + cs * 16 + (lane & 15);
    int k0   = kc * 32 + ((lane >> 4) << 3);
    const float* src = fcw + col * 128 + k0;
    unsigned int u[4];
#pragma unroll
    for (int j = 0; j < 4; ++j)
        u[j] = (unsigned int)f2bf(src[2 * j]) | ((unsigned int)f2bf(src[2 * j + 1]) << 16);
    *(uint4*)(dst + frag * 512 + lane * 8) = make_uint4(u[0], u[1], u[2], u[3]);
}

// Quantize out_w [2,256] -> i8 proj B-frags [slice4][lane][16B] + row scales.
__global__ void pack_outw_i8(const float* __restrict__ out_w,
                             signed char* __restrict__ dst, float* __restrict__ swout) {
    __shared__ float sw[2];
    int tid = threadIdx.x;
    if (tid < 128) {
        int o = tid >> 6, lane = tid & 63;
        const float* src = out_w + o * 256 + lane * 4;
        float m = 0.0f;
#pragma unroll
        for (int j = 0; j < 4; ++j) m = fmaxf(m, fabsf(src[j]));
#pragma unroll
        for (int d = 1; d < 64; d <<= 1) m = fmaxf(m, __shfl_xor(m, d, 64));
        if (lane == 0) { sw[o] = m; swout[o] = m; }
    }
    __syncthreads();
    int sl = tid >> 6, lane = tid & 63;
    int n  = lane & 15;
    int k0 = sl * 64 + ((lane >> 4) << 4);
    signed char q[16];
#pragma unroll
    for (int j = 0; j < 16; ++j) {
        float v = 0.0f;
        if (n < 2) {
            v = __builtin_rintf(out_w[n * 256 + k0 + j] * (127.0f / sw[n]));
            v = fminf(fmaxf(v, -127.0f), 127.0f);
        }
        q[j] = (signed char)(int)v;
    }
    *(intx4*)(dst + sl * 1024 + lane * 16) = *(intx4*)q;
}

// Persistent GRU r28: RESTORE r22 (best: 440.3us) + two unconfounded
// micro-levers. r27 closed the occupancy axis by arithmetic: 8 waves/SIMD
// needs <=64 regs/wave but weights alone are 48; weights-in-LDS needs
// 192KB/block > 160KB/CU; weight reload from L2/HBM (r27: 7.1GB/dispatch)
// costs 4x the idle it recovers. 4 waves/SIMD is the hard envelope.
// vs r22: (a) flush spread across waves 8-15 x 8 lanes (r22 serialized
// 15 waves behind wave 8's 4-read+store straggler; previously only tested
// bundled with the r24 swizzle), (b) s_setprio(1) around the MFMA runs
// (never tested standalone on this skew). No layout changes.
__global__ __launch_bounds__(1024, 4) void gru_main(
    const float* __restrict__ z,
    const float* __restrict__ fc_b,
    const float* __restrict__ b_ih,
    const float* __restrict__ b_hh,
    const float* __restrict__ out_b,
    const unsigned char* __restrict__ ws,
    float* __restrict__ out)
{
    extern __shared__ unsigned char smem[];
    signed char* h8a   = (signed char*)smem;                 // buf parity 0
    signed char* h8b   = (signed char*)(smem + H8B_OFF);     // buf parity 1
    int*         obufI = (int*)(smem + OBUF_OFF);            // [rh2][sl4][16][2]

    const int tid  = threadIdx.x;
    const int lane = tid & 63;
    const int wv   = tid >> 6;       // 0..15
    const int cg   = wv;             // 16-col group owned by this wave
    const int l15  = lane & 15;
    const int qd   = lane >> 4;
    const int rh   = (wv >> 2) & 1;  // proj row-half (waves 0-7)
    const int sl   = wv & 3;         // proj 64-col k-slice
    const int rb   = blockIdx.x * 32;

    const intx4 zero4 = (intx4){0, 0, 0, 0};   // persistent MFMA C-init

    // ---- ALL 3 gates' i8 weight frags into registers (12 frags = 48 VGPRs) ----
    intx4 wq[12];
#pragma unroll
    for (int g = 0; g < 3; ++g)
#pragma unroll
        for (int kc = 0; kc < 4; ++kc)
            wq[g * 4 + kc] = *(const intx4*)(ws + WQ_OFF
                + (size_t)((((cg >> 1) * 6 + g * 2 + (cg & 1)) * 4 + kc)) * 1024 + lane * 16);

    // ---- proj B-frag (i8; meaningful on waves 0-7) + per-lane constants ----
    intx4 bproj = *(const intx4*)(ws + OUTW_OFF + sl * 1024 + lane * 16);
    const float* swout = (const float*)(ws + SWOUT_OFF);
    float pscF = swout[lane & 1] * (1.0f / 16129.0f);   // flush scale (o = lane&1)

    const float* scales = (const float*)(ws + SCW_OFF);
    float fcbE2;
    float2v nscqr2, ncbr2, nscqz2, ncbz2, scqn2, bhn2, bin2;
    {
        int col = cg * 16 + l15;
        float ncbrE  = -(b_ih[col]       + b_hh[col])       * LOG2E;
        float ncbzE  = -(b_ih[256 + col] + b_hh[256 + col]) * LOG2E;
        float binE2  = b_ih[512 + col] * (2.0f * LOG2E);
        float bhnE2  = b_hh[512 + col] * (2.0f * LOG2E);
        fcbE2  = fc_b[col] * (2.0f * LOG2E);
        float nscqrE = -scales[col]       * (LOG2E / 16129.0f);
        float nscqzE = -scales[256 + col] * (LOG2E / 16129.0f);
        float scqnE2 = scales[512 + col] * (2.0f * LOG2E / 16129.0f);
        nscqr2 = (float2v){nscqrE, nscqrE};  ncbr2 = (float2v){ncbrE, ncbrE};
        nscqz2 = (float2v){nscqzE, nscqzE};  ncbz2 = (float2v){ncbzE, ncbzE};
        scqn2  = (float2v){scqnE2, scqnE2};  bhn2  = (float2v){bhnE2, bhnE2};
        bin2   = (float2v){binE2, binE2};
    }
    const float2v m254 = (float2v){-254.0f, -254.0f};
    const float2v p127 = (float2v){127.0f, 127.0f};
    float ob = out_b[lane & 1];

    // hoisted LDS byte offsets (one base reg + compile-time imms per access)
    const int rdOff = l15 * H8_STRIDE + qd * 16;                    // A-frag reads
    const int pjOff = (rh * 16 + l15) * H8_STRIDE + sl * 64 + qd * 16;  // proj read
    const int wrOff = (qd * 4) * H8_STRIDE + cg * 16 + l15;         // h stores

    // spread flush bookkeeping: waves 8-15, lanes 0-7 (8 lanes x 8 waves = 64)
    const int rlW = ((wv - 8) * 4 + (lane >> 1)) & 31;
    const int o8  = lane & 1;
    const int fbase = (rlW >> 4) * 128 + (rlW & 15) * 2 + o8;
    float* opW8 = out + (size_t)(rb + rlW) * (T_SEQ * 2) + o8;   // -> out idx 0

    // ---- h0 = tanh(fc(z)) kept x127: bf16 MFMA, A-frags direct from global ----
    floatx4 a0f[2];
#pragma unroll
    for (int rt = 0; rt < 2; ++rt) a0f[rt] = (floatx4){0.f, 0.f, 0.f, 0.f};
#pragma unroll
    for (int kc = 0; kc < 4; ++kc) {
        short8 bfr = *(const short8*)(ws + FCW_OFF + (size_t)(cg * 4 + kc) * 1024 + lane * 16);
#pragma unroll
        for (int rt = 0; rt < 2; ++rt) {
            const float* zp = z + (size_t)(rb + rt * 16 + l15) * LATENT + kc * 32 + qd * 8;
            short8 afr;
#pragma unroll
            for (int j = 0; j < 8; ++j) afr[j] = (short)f2bf(zp[j]);
            a0f[rt] = __builtin_amdgcn_mfma_f32_16x16x32_bf16(afr, bfr, a0f[rt], 0, 0, 0);
        }
    }

    float2v hm2[2][2];   // 127-scaled hidden state, packed in r-pairs
#pragma unroll
    for (int rt = 0; rt < 2; ++rt)
#pragma unroll
        for (int r = 0; r < 4; ++r) {
            float u = __builtin_amdgcn_rcpf(1.0f + __builtin_amdgcn_exp2f(
                          __builtin_fmaf(a0f[rt][r], 2.0f * LOG2E, fcbE2)));
            float h = __builtin_fmaf(-254.0f, u, 127.0f);   // 127*tanh(.)
            hm2[rt][r >> 1][r & 1] = h;
            h8a[(rt * 16 + qd * 4 + r) * H8_STRIDE + cg * 16 + l15] =
                (signed char)__float_as_uint(h + 12582912.0f);   // RNE int8 low byte
        }
    __syncthreads();

    intx4 acc0[3], acc1[3];

#define MFI8(A, B, C) __builtin_amdgcn_mfma_i32_16x16x64_i8((A), (B), (C), 0, 0, 0)

    // one PACKED h-update pair (rows 2P, 2P+1): acc -> gates -> h -> i8 stores.
#define HUPD_PAIR(ACC, RT, P, WP)                                                 \
    {                                                                             \
        float2v arv, azv, anv;                                                    \
        arv[0] = (float)(ACC)[0][2*(P)];   arv[1] = (float)(ACC)[0][2*(P)+1];     \
        azv[0] = (float)(ACC)[1][2*(P)];   azv[1] = (float)(ACC)[1][2*(P)+1];     \
        anv[0] = (float)(ACC)[2][2*(P)];   anv[1] = (float)(ACC)[2][2*(P)+1];     \
        float2v yr = __builtin_elementwise_fma(arv, nscqr2, ncbr2);               \
        float2v yz = __builtin_elementwise_fma(azv, nscqz2, ncbz2);               \
        float2v Ar, Az;                                                           \
        Ar[0] = __builtin_amdgcn_exp2f(yr[0]); Ar[1] = __builtin_amdgcn_exp2f(yr[1]); \
        Az[0] = __builtin_amdgcn_exp2f(yz[0]); Az[1] = __builtin_amdgcn_exp2f(yz[1]); \
        float2v dr = Ar + 1.0f, dz = Az + 1.0f;                                   \
        float2v pr = dr * dz;                                                     \
        float2v q_;                                                               \
        q_[0] = __builtin_amdgcn_rcpf(pr[0]); q_[1] = __builtin_amdgcn_rcpf(pr[1]); \
        float2v gr = q_ * dz, gz = q_ * dr;                                       \
        float2v xn2 = __builtin_elementwise_fma(anv, scqn2, bhn2);                \
        float2v tt  = __builtin_elementwise_fma(gr, xn2, bin2);                   \
        float2v Ee, uu;                                                           \
        Ee[0] = __builtin_amdgcn_exp2f(tt[0]); Ee[1] = __builtin_amdgcn_exp2f(tt[1]); \
        Ee = Ee + 1.0f;                                                           \
        uu[0] = __builtin_amdgcn_rcpf(Ee[0]); uu[1] = __builtin_amdgcn_rcpf(Ee[1]); \
        float2v gn = __builtin_elementwise_fma(m254, uu, p127);                   \
        float2v hv = hm2[RT][P];                                                  \
        float2v hn = __builtin_elementwise_fma(gz, hv - gn, gn);                  \
        hm2[RT][P] = hn;                                                          \
        float2v hb = hn + 12582912.0f;                                            \
        (WP)[(2*(P))   * H8_STRIDE] = (signed char)__float_as_uint(hb[0]);        \
        (WP)[(2*(P)+1) * H8_STRIDE] = (signed char)__float_as_uint(hb[1]);        \
    }

    // region A: MFMA rt0 (reads BUF rows 0-15) || VALU rt1 (prev acc1) ->
    // h1(t) stores (BUF rows 16-31) || flush (waves 8-15 lanes 0-7, out t-2)
#define REGION_A(BUF, DO_V1, DO_FLUSH)                                           \
    {                                                                            \
        const signed char* rp = (BUF) + rdOff;                                   \
        signed char*       wp = (BUF) + wrOff + 16 * H8_STRIDE;                  \
        __builtin_amdgcn_s_setprio(1);                                           \
        intx4 a8 = *(const intx4*)(rp);                                          \
        acc0[0] = MFI8(a8, wq[0], zero4);                                        \
        acc0[1] = MFI8(a8, wq[4], zero4);                                        \
        acc0[2] = MFI8(a8, wq[8], zero4);                                        \
        __builtin_amdgcn_s_setprio(0);                                           \
        if (DO_V1) { HUPD_PAIR(acc1, 1, 0, wp) }                                 \
        __builtin_amdgcn_s_setprio(1);                                           \
        a8 = *(const intx4*)(rp + 64);                                           \
        acc0[0] = MFI8(a8, wq[1], acc0[0]);                                      \
        acc0[1] = MFI8(a8, wq[5], acc0[1]);                                      \
        acc0[2] = MFI8(a8, wq[9], acc0[2]);                                      \
        __builtin_amdgcn_s_setprio(0);                                           \
        if (DO_V1) { HUPD_PAIR(acc1, 1, 1, wp) }                                 \
        __builtin_amdgcn_s_setprio(1);                                           \
        a8 = *(const intx4*)(rp + 128);                                          \
        acc0[0] = MFI8(a8, wq[2], acc0[0]);                                      \
        acc0[1] = MFI8(a8, wq[6], acc0[1]);                                      \
        acc0[2] = MFI8(a8, wq[10], acc0[2]);                                     \
        __builtin_amdgcn_s_setprio(0);                                           \
        if (DO_FLUSH && wv >= 8 && lane < 8) {                                   \
            int s_ = obufI[fbase] + obufI[fbase + 32]                            \
                   + obufI[fbase + 64] + obufI[fbase + 96];                      \
            *opW8 = __builtin_fmaf((float)s_, pscF, ob);                         \
            opW8 += 2;                                                           \
        }                                                                        \
        __builtin_amdgcn_s_setprio(1);                                           \
        a8 = *(const intx4*)(rp + 192);                                          \
        acc0[0] = MFI8(a8, wq[3], acc0[0]);                                      \
        acc0[1] = MFI8(a8, wq[7], acc0[1]);                                      \
        acc0[2] = MFI8(a8, wq[11], acc0[2]);                                     \
        __builtin_amdgcn_s_setprio(0);                                           \
        __syncthreads();                                                         \
    }

    // region C: MFMA rt1 (reads BUFR rows 16-31) + proj(t) || VALU rt0 ->
    // h0(t+1) stores (BUFW rows 0-15) || stash pj
#define REGION_C(BUFR, BUFW, DO_PJ)                                              \
    {                                                                            \
        const signed char* rp = (BUFR) + rdOff + 16 * H8_STRIDE;                 \
        signed char*       wp = (BUFW) + wrOff;                                  \
        intx4 pj;                                                                \
        if (DO_PJ && wv < 8) {                                                   \
            intx4 a8p = *(const intx4*)((BUFR) + pjOff);                         \
            pj = MFI8(a8p, bproj, zero4);                                        \
        }                                                                        \
        __builtin_amdgcn_s_setprio(1);                                           \
        intx4 a8 = *(const intx4*)(rp);                                          \
        acc1[0] = MFI8(a8, wq[0], zero4);                                        \
        acc1[1] = MFI8(a8, wq[4], zero4);                                        \
        acc1[2] = MFI8(a8, wq[8], zero4);                                        \
        __builtin_amdgcn_s_setprio(0);                                           \
        HUPD_PAIR(acc0, 0, 0, wp)                                                \
        __builtin_amdgcn_s_setprio(1);                                           \
        a8 = *(const intx4*)(rp + 64);                                           \
        acc1[0] = MFI8(a8, wq[1], acc1[0]);                                      \
        acc1[1] = MFI8(a8, wq[5], acc1[1]);                                      \
        acc1[2] = MFI8(a8, wq[9], acc1[2]);                                      \
        __builtin_amdgcn_s_setprio(0);                                           \
        HUPD_PAIR(acc0, 0, 1, wp)                                                \
        __builtin_amdgcn_s_setprio(1);                                           \
        a8 = *(const intx4*)(rp + 128);                                          \
        acc1[0] = MFI8(a8, wq[2], acc1[0]);                                      \
        acc1[1] = MFI8(a8, wq[6], acc1[1]);                                      \
        acc1[2] = MFI8(a8, wq[10], acc1[2]);                                     \
        a8 = *(const intx4*)(rp + 192);                                          \
        acc1[0] = MFI8(a8, wq[3], acc1[0]);                                      \
        acc1[1] = MFI8(a8, wq[7], acc1[1]);                                      \
        acc1[2] = MFI8(a8, wq[11], acc1[2]);                                     \
        __builtin_amdgcn_s_setprio(0);                                           \
        if (DO_PJ && wv < 8 && l15 < 2) {                                        \
            _Pragma("unroll")                                                    \
            for (int r = 0; r < 4; ++r)                                          \
                obufI[(rh * 4 + sl) * 32 + (qd * 4 + r) * 2 + l15] = pj[r];      \
        }                                                                        \
        __syncthreads();                                                         \
    }

    // ---- prologue: t=0,1 peeled ----
    REGION_A(h8a, 0, 0)        // A(0): MFMA0(0) only
    REGION_C(h8a, h8b, 0)      // C(0): MFMA1(0); h0(1)->buf1
    REGION_A(h8b, 1, 0)        // A(1): MFMA0(1); h1(1)->buf1
    REGION_C(h8b, h8a, 1)      // C(1): MFMA1(1); proj(1) stash; h0(2)->buf0

    // ---- steady state: t = 2..179, 89 parity pairs ----
#pragma unroll 1
    for (int t2 = 0; t2 < 89; ++t2) {
        REGION_A(h8a, 1, 1)    // even t: flush out[t-2]
        REGION_C(h8a, h8b, 1)
        REGION_A(h8b, 1, 1)    // odd t+1: flush out[t-1]
        REGION_C(h8b, h8a, 1)
    }

    // ---- epilogue ----
    {   // E1: VALU1(179) -> h1(180) -> buf0; flush stash(179) -> out idx 178
        signed char* wp = h8a + wrOff + 16 * H8_STRIDE;
        HUPD_PAIR(acc1, 1, 0, wp)
        HUPD_PAIR(acc1, 1, 1, wp)
        if (wv >= 8 && lane < 8) {
            int s_ = obufI[fbase] + obufI[fbase + 32]
                   + obufI[fbase + 64] + obufI[fbase + 96];
            *opW8 = __builtin_fmaf((float)s_, pscF, ob);
            opW8 += 2;
        }
        __syncthreads();
    }
    // E2: proj(180) read buf0 -> stash
    if (wv < 8) {
        intx4 a8p = *(const intx4*)(h8a + pjOff);
        intx4 pj = MFI8(a8p, bproj, zero4);
        if (l15 < 2)
#pragma unroll
            for (int r = 0; r < 4; ++r)
                obufI[(rh * 4 + sl) * 32 + (qd * 4 + r) * 2 + l15] = pj[r];
    }
    __syncthreads();
    // E3: flush -> out idx 179
    if (wv >= 8 && lane < 8) {
        int s_ = obufI[fbase] + obufI[fbase + 32]
               + obufI[fbase + 64] + obufI[fbase + 96];
        *opW8 = __builtin_fmaf((float)s_, pscF, ob);
    }
#undef REGION_C
#undef REGION_A
#undef HUPD_PAIR
#undef MFI8
}

extern "C" void kernel_launch(void* const* d_in, const int* in_sizes, int n_in,
                              void* d_out, int out_size, void* d_ws, size_t ws_size,
                              hipStream_t stream) {
    const float* z     = (const float*)d_in[0];
    const float* fc_w  = (const float*)d_in[1];
    const float* fc_b  = (const float*)d_in[2];
    // d_in[3] = w_ih : unused (GRU input is all-zeros, gi = b_ih)
    const float* b_ih  = (const float*)d_in[4];
    const float* w_hh  = (const float*)d_in[5];
    const float* b_hh  = (const float*)d_in[6];
    const float* out_w = (const float*)d_in[7];
    const float* out_b = (const float*)d_in[8];
    float* out = (float*)d_out;
    unsigned char* ws = (unsigned char*)d_ws;   // needs 269,320 B

    hipFuncSetAttribute((const void*)gru_main,
                        hipFuncAttributeMaxDynamicSharedMemorySize, SMEM_BYTES);

    pack_scales<<<192, 256, 0, stream>>>(w_hh, (float*)(ws + SCW_OFF));
    pack_whh_i8<<<48, 256, 0, stream>>>(w_hh, (const float*)(ws + SCW_OFF),
                                        (signed char*)(ws + WQ_OFF));
    pack_fcw<<<16, 256, 0, stream>>>(fc_w, (unsigned short*)(ws + FCW_OFF));
    pack_outw_i8<<<1, 256, 0, stream>>>(out_w, (signed char*)(ws + OUTW_OFF),
                                        (float*)(ws + SWOUT_OFF));
    gru_main<<<256, 1024, SMEM_BYTES, stream>>>(z, fc_b, b_ih, b_hh, out_b, ws, out);
}

// Round 10
// 457.944 us; speedup vs baseline: 4.3654x; 1.0363x over previous
//
#include <hip/hip_runtime.h>
#include <hip/hip_bf16.h>

#define T_SEQ  180
#define LATENT 128
#define HIDDEN 256

typedef __attribute__((ext_vector_type(8))) short  short8;   // 8 x bf16 (4 VGPRs)
typedef __attribute__((ext_vector_type(4))) float  floatx4;  // f32 MFMA acc
typedef __attribute__((ext_vector_type(4))) int    intx4;    // i8 frag / i32 acc
typedef __attribute__((ext_vector_type(2))) float  float2v;  // packed f32 (v_pk_*)

#define LOG2E 1.4426950408889634f

// ---- d_ws layout (BYTES) ----
#define WQ_OFF    0        // w_hh i8 frags: ((w*6+sub)*4+kc)*1024, 192 KB
#define FCW_OFF   196608   // fc_w bf16 frags (r9/r13 layout), 64 KB
#define SCW_OFF   262144   // w_hh row scales: float[768]
#define OUTW_OFF  265216   // out_w i8 frags: [slice4][lane64][16B] = 4096 B
#define SWOUT_OFF 269312   // out_w row scales: float[2]

// ---- dynamic LDS layout (bytes) ----
// h ping-pong: 2 x 32 rows x 272 B; obuf single [rh2][sl4][16][2] int32
#define H8_STRIDE  272
#define H8B_OFF    8704
#define OBUF_OFF   17408
#define SMEM_BYTES 18432

__device__ __forceinline__ unsigned short f2bf(float f) {
    unsigned int u = __float_as_uint(f);
    u += 0x7fffu + ((u >> 16) & 1u);      // round-to-nearest-even
    return (unsigned short)(u >> 16);
}

// Per-output-unit scales: one wave per row j of w_hh.
__global__ void pack_scales(const float* __restrict__ whh, float* __restrict__ scales) {
    int wid  = blockIdx.x * 4 + (threadIdx.x >> 6);   // 0..767
    int lane = threadIdx.x & 63;
    const float* src = whh + (size_t)wid * 256 + lane * 4;
    float m = 0.0f;
#pragma unroll
    for (int j = 0; j < 4; ++j) m = fmaxf(m, fabsf(src[j]));
#pragma unroll
    for (int d = 1; d < 64; d <<= 1) m = fmaxf(m, __shfl_xor(m, d, 64));
    if (lane == 0) scales[wid] = m;
}

// Pack w_hh [768,256] fp32 -> i8 16x16x64 B-frags (r13-verified layout).
__global__ void pack_whh_i8(const float* __restrict__ whh, const float* __restrict__ scales,
                            signed char* __restrict__ dst) {
    int tid  = blockIdx.x * blockDim.x + threadIdx.x;  // 12288 threads
    int lane = tid & 63;
    int frag = tid >> 6;                               // 0..191
    int kc   = frag & 3;
    int sub  = (frag >> 2) % 6;
    int w    = frag / 24;
    int g = sub >> 1, cs = sub & 1;
    int col  = w * 32 + cs * 16 + (lane & 15);
    int jout = g * 256 + col;
    int k0   = kc * 64 + ((lane >> 4) << 4);
    const float* src = whh + (size_t)jout * 256 + k0;
    float inv = 127.0f / scales[jout];
    signed char q[16];
#pragma unroll
    for (int j = 0; j < 16; ++j) {
        float v = __builtin_rintf(src[j] * inv);
        v = fminf(fmaxf(v, -127.0f), 127.0f);
        q[j] = (signed char)(int)v;
    }
    *(intx4*)(dst + (size_t)frag * 1024 + lane * 16) = *(intx4*)q;
}

// Pack fc_w [256,128] fp32 -> bf16 16x16x32 B-frags (r9 layout).
__global__ void pack_fcw(const float* __restrict__ fcw, unsigned short* __restrict__ dst) {
    int tid  = blockIdx.x * blockDim.x + threadIdx.x;  // 4096 threads
    int lane = tid & 63;
    int frag = tid >> 6;                               // 0..63
    int kc   = frag & 3;
    int cs   = (frag >> 2) & 1;
    int w    = frag >> 3;
    int col  = w * 32 + cs * 16 + (lane & 15);
    int k0   = kc * 32 + ((lane >> 4) << 3);
    const float* src = fcw + col * 128 + k0;
    unsigned int u[4];
#pragma unroll
    for (int j = 0; j < 4; ++j)
        u[j] = (unsigned int)f2bf(src[2 * j]) | ((unsigned int)f2bf(src[2 * j + 1]) << 16);
    *(uint4*)(dst + frag * 512 + lane * 8) = make_uint4(u[0], u[1], u[2], u[3]);
}

// Quantize out_w [2,256] -> i8 proj B-frags [slice4][lane][16B] + row scales.
__global__ void pack_outw_i8(const float* __restrict__ out_w,
                             signed char* __restrict__ dst, float* __restrict__ swout) {
    __shared__ float sw[2];
    int tid = threadIdx.x;
    if (tid < 128) {
        int o = tid >> 6, lane = tid & 63;
        const float* src = out_w + o * 256 + lane * 4;
        float m = 0.0f;
#pragma unroll
        for (int j = 0; j < 4; ++j) m = fmaxf(m, fabsf(src[j]));
#pragma unroll
        for (int d = 1; d < 64; d <<= 1) m = fmaxf(m, __shfl_xor(m, d, 64));
        if (lane == 0) { sw[o] = m; swout[o] = m; }
    }
    __syncthreads();
    int sl = tid >> 6, lane = tid & 63;
    int n  = lane & 15;
    int k0 = sl * 64 + ((lane >> 4) << 4);
    signed char q[16];
#pragma unroll
    for (int j = 0; j < 16; ++j) {
        float v = 0.0f;
        if (n < 2) {
            v = __builtin_rintf(out_w[n * 256 + k0 + j] * (127.0f / sw[n]));
            v = fminf(fmaxf(v, -127.0f), 127.0f);
        }
        q[j] = (signed char)(int)v;
    }
    *(intx4*)(dst + sl * 1024 + lane * 16) = *(intx4*)q;
}

// Persistent GRU r29 = r22 RESTORED VERBATIM (session best: 440.3 us rocprof).
// 10-structure ledger closed every axis: issue-count shaves convert at only
// ~0.18x to time; skew/monolithic/heterogeneous/setprio schedules all +/-3%;
// SQ_LDS_BANK_CONFLICT (2.507e7) is a fixed ds_read_b128 multi-cycle artifact
// (4 cyc x 136 reads/CU/step, address-invariant; narrowing reads = 1.8x worse);
// occupancy >4 waves/SIMD is infeasible by register arithmetic (weights=48
// VGPR; weights-in-LDS needs 192KB>160KB; refetch costs 7.1GB HBM traffic).
// The ~5100 cyc/step is ~2000 cyc MFMA floor (100x 16x16x64-i8 per SIMD at
// ubench rate) + ~1800 cyc packed-minimal VALU + serial recurrence latency
// that 4 barrier-locked waves cannot hide. Structural floor for this design.
// Structure: 2-region skew (rt0/rt1 half-step pipeline), packed f32 HUPD,
// zero4 MFMA C-operand, single obuf, imm offsets, magic-constant f32->i8.
__global__ __launch_bounds__(1024, 4) void gru_main(
    const float* __restrict__ z,
    const float* __restrict__ fc_b,
    const float* __restrict__ b_ih,
    const float* __restrict__ b_hh,
    const float* __restrict__ out_b,
    const unsigned char* __restrict__ ws,
    float* __restrict__ out)
{
    extern __shared__ unsigned char smem[];
    signed char* h8a   = (signed char*)smem;                 // buf parity 0
    signed char* h8b   = (signed char*)(smem + H8B_OFF);     // buf parity 1
    int*         obufI = (int*)(smem + OBUF_OFF);            // [rh2][sl4][16][2]

    const int tid  = threadIdx.x;
    const int lane = tid & 63;
    const int wv   = tid >> 6;       // 0..15
    const int cg   = wv;             // 16-col group owned by this wave
    const int l15  = lane & 15;
    const int qd   = lane >> 4;
    const int rh   = (wv >> 2) & 1;  // proj row-half (waves 0-7)
    const int sl   = wv & 3;         // proj 64-col k-slice
    const int rb   = blockIdx.x * 32;

    const intx4 zero4 = (intx4){0, 0, 0, 0};   // persistent MFMA C-init

    // ---- ALL 3 gates' i8 weight frags into registers (12 frags = 48 VGPRs) ----
    intx4 wq[12];
#pragma unroll
    for (int g = 0; g < 3; ++g)
#pragma unroll
        for (int kc = 0; kc < 4; ++kc)
            wq[g * 4 + kc] = *(const intx4*)(ws + WQ_OFF
                + (size_t)((((cg >> 1) * 6 + g * 2 + (cg & 1)) * 4 + kc)) * 1024 + lane * 16);

    // ---- proj B-frag (i8; meaningful on waves 0-7) + per-lane constants ----
    intx4 bproj = *(const intx4*)(ws + OUTW_OFF + sl * 1024 + lane * 16);
    const float* swout = (const float*)(ws + SWOUT_OFF);
    float pscF = swout[tid & 1] * (1.0f / 16129.0f);   // flush scale (by o = tid&1)

    const float* scales = (const float*)(ws + SCW_OFF);
    float fcbE2;
    float2v nscqr2, ncbr2, nscqz2, ncbz2, scqn2, bhn2, bin2;
    {
        int col = cg * 16 + l15;
        float ncbrE  = -(b_ih[col]       + b_hh[col])       * LOG2E;
        float ncbzE  = -(b_ih[256 + col] + b_hh[256 + col]) * LOG2E;
        float binE2  = b_ih[512 + col] * (2.0f * LOG2E);
        float bhnE2  = b_hh[512 + col] * (2.0f * LOG2E);
        fcbE2  = fc_b[col] * (2.0f * LOG2E);
        float nscqrE = -scales[col]       * (LOG2E / 16129.0f);
        float nscqzE = -scales[256 + col] * (LOG2E / 16129.0f);
        float scqnE2 = scales[512 + col] * (2.0f * LOG2E / 16129.0f);
        nscqr2 = (float2v){nscqrE, nscqrE};  ncbr2 = (float2v){ncbrE, ncbrE};
        nscqz2 = (float2v){nscqzE, nscqzE};  ncbz2 = (float2v){ncbzE, ncbzE};
        scqn2  = (float2v){scqnE2, scqnE2};  bhn2  = (float2v){bhnE2, bhnE2};
        bin2   = (float2v){binE2, binE2};
    }
    const float2v m254 = (float2v){-254.0f, -254.0f};
    const float2v p127 = (float2v){127.0f, 127.0f};
    float ob = out_b[tid & 1];

    // hoisted LDS byte offsets (one base reg + compile-time imms per access)
    const int rdOff = l15 * H8_STRIDE + qd * 16;                    // A-frag reads
    const int pjOff = (rh * 16 + l15) * H8_STRIDE + sl * 64 + qd * 16;  // proj read
    const int wrOff = (qd * 4) * H8_STRIDE + cg * 16 + l15;         // h stores

    // wave-8 flush bookkeeping (junk on other threads; never dereferenced)
    const int rlW = ((tid - 512) >> 1) & 31;
    const int o8  = tid & 1;
    const int fbase = (rlW >> 4) * 128 + (rlW & 15) * 2 + o8;
    float* opW8 = out + (size_t)(rb + rlW) * (T_SEQ * 2) + o8;   // -> out idx 0

    // ---- h0 = tanh(fc(z)) kept x127: bf16 MFMA, A-frags direct from global ----
    floatx4 a0f[2];
#pragma unroll
    for (int rt = 0; rt < 2; ++rt) a0f[rt] = (floatx4){0.f, 0.f, 0.f, 0.f};
#pragma unroll
    for (int kc = 0; kc < 4; ++kc) {
        short8 bfr = *(const short8*)(ws + FCW_OFF + (size_t)(cg * 4 + kc) * 1024 + lane * 16);
#pragma unroll
        for (int rt = 0; rt < 2; ++rt) {
            const float* zp = z + (size_t)(rb + rt * 16 + l15) * LATENT + kc * 32 + qd * 8;
            short8 afr;
#pragma unroll
            for (int j = 0; j < 8; ++j) afr[j] = (short)f2bf(zp[j]);
            a0f[rt] = __builtin_amdgcn_mfma_f32_16x16x32_bf16(afr, bfr, a0f[rt], 0, 0, 0);
        }
    }

    float2v hm2[2][2];   // 127-scaled hidden state, packed in r-pairs
#pragma unroll
    for (int rt = 0; rt < 2; ++rt)
#pragma unroll
        for (int r = 0; r < 4; ++r) {
            float u = __builtin_amdgcn_rcpf(1.0f + __builtin_amdgcn_exp2f(
                          __builtin_fmaf(a0f[rt][r], 2.0f * LOG2E, fcbE2)));
            float h = __builtin_fmaf(-254.0f, u, 127.0f);   // 127*tanh(.)
            hm2[rt][r >> 1][r & 1] = h;
            h8a[(rt * 16 + qd * 4 + r) * H8_STRIDE + cg * 16 + l15] =
                (signed char)__float_as_uint(h + 12582912.0f);   // RNE int8 low byte
        }
    __syncthreads();

    intx4 acc0[3], acc1[3];

    // one PACKED h-update pair (rows 2P, 2P+1): acc -> gates -> h -> i8 stores.
    // pk ops (v_pk_fma/add/mul_f32) halve the non-trans f32 issue count.
#define HUPD_PAIR(ACC, RT, P, WP)                                                 \
    {                                                                             \
        float2v arv, azv, anv;                                                    \
        arv[0] = (float)(ACC)[0][2*(P)];   arv[1] = (float)(ACC)[0][2*(P)+1];     \
        azv[0] = (float)(ACC)[1][2*(P)];   azv[1] = (float)(ACC)[1][2*(P)+1];     \
        anv[0] = (float)(ACC)[2][2*(P)];   anv[1] = (float)(ACC)[2][2*(P)+1];     \
        float2v yr = __builtin_elementwise_fma(arv, nscqr2, ncbr2);               \
        float2v yz = __builtin_elementwise_fma(azv, nscqz2, ncbz2);               \
        float2v Ar, Az;                                                           \
        Ar[0] = __builtin_amdgcn_exp2f(yr[0]); Ar[1] = __builtin_amdgcn_exp2f(yr[1]); \
        Az[0] = __builtin_amdgcn_exp2f(yz[0]); Az[1] = __builtin_amdgcn_exp2f(yz[1]); \
        float2v dr = Ar + 1.0f, dz = Az + 1.0f;                                   \
        float2v pr = dr * dz;                                                     \
        float2v q_;                                                               \
        q_[0] = __builtin_amdgcn_rcpf(pr[0]); q_[1] = __builtin_amdgcn_rcpf(pr[1]); \
        float2v gr = q_ * dz, gz = q_ * dr;                                       \
        float2v xn2 = __builtin_elementwise_fma(anv, scqn2, bhn2);                \
        float2v tt  = __builtin_elementwise_fma(gr, xn2, bin2);                   \
        float2v Ee, uu;                                                           \
        Ee[0] = __builtin_amdgcn_exp2f(tt[0]); Ee[1] = __builtin_amdgcn_exp2f(tt[1]); \
        Ee = Ee + 1.0f;                                                           \
        uu[0] = __builtin_amdgcn_rcpf(Ee[0]); uu[1] = __builtin_amdgcn_rcpf(Ee[1]); \
        float2v gn = __builtin_elementwise_fma(m254, uu, p127);                   \
        float2v hv = hm2[RT][P];                                                  \
        float2v hn = __builtin_elementwise_fma(gz, hv - gn, gn);                  \
        hm2[RT][P] = hn;                                                          \
        float2v hb = hn + 12582912.0f;                                            \
        (WP)[(2*(P))   * H8_STRIDE] = (signed char)__float_as_uint(hb[0]);        \
        (WP)[(2*(P)+1) * H8_STRIDE] = (signed char)__float_as_uint(hb[1]);        \
    }

    // region A: MFMA rt0 (reads BUF rows 0-15) || VALU rt1 (prev acc1) ->
    // h1(t) stores (BUF rows 16-31) || flush (wave 8, out idx t-2)
#define REGION_A(BUF, DO_V1, DO_FLUSH)                                           \
    {                                                                            \
        const signed char* rp = (BUF) + rdOff;                                   \
        signed char*       wp = (BUF) + wrOff + 16 * H8_STRIDE;                  \
        intx4 a8 = *(const intx4*)(rp);                                          \
        acc0[0] = __builtin_amdgcn_mfma_i32_16x16x64_i8(a8, wq[0], zero4,   0, 0, 0); \
        acc0[1] = __builtin_amdgcn_mfma_i32_16x16x64_i8(a8, wq[4], zero4,   0, 0, 0); \
        acc0[2] = __builtin_amdgcn_mfma_i32_16x16x64_i8(a8, wq[8], zero4,   0, 0, 0); \
        if (DO_V1) { HUPD_PAIR(acc1, 1, 0, wp) }                                 \
        a8 = *(const intx4*)(rp + 64);                                           \
        acc0[0] = __builtin_amdgcn_mfma_i32_16x16x64_i8(a8, wq[1], acc0[0], 0, 0, 0); \
        acc0[1] = __builtin_amdgcn_mfma_i32_16x16x64_i8(a8, wq[5], acc0[1], 0, 0, 0); \
        acc0[2] = __builtin_amdgcn_mfma_i32_16x16x64_i8(a8, wq[9], acc0[2], 0, 0, 0); \
        if (DO_V1) { HUPD_PAIR(acc1, 1, 1, wp) }                                 \
        a8 = *(const intx4*)(rp + 128);                                          \
        acc0[0] = __builtin_amdgcn_mfma_i32_16x16x64_i8(a8, wq[2], acc0[0], 0, 0, 0); \
        acc0[1] = __builtin_amdgcn_mfma_i32_16x16x64_i8(a8, wq[6], acc0[1], 0, 0, 0); \
        acc0[2] = __builtin_amdgcn_mfma_i32_16x16x64_i8(a8, wq[10], acc0[2], 0, 0, 0); \
        if (DO_FLUSH && tid >= 512 && tid < 576) {                               \
            int s_ = obufI[fbase] + obufI[fbase + 32]                            \
                   + obufI[fbase + 64] + obufI[fbase + 96];                      \
            *opW8 = __builtin_fmaf((float)s_, pscF, ob);                         \
            opW8 += 2;                                                           \
        }                                                                        \
        a8 = *(const intx4*)(rp + 192);                                          \
        acc0[0] = __builtin_amdgcn_mfma_i32_16x16x64_i8(a8, wq[3], acc0[0], 0, 0, 0); \
        acc0[1] = __builtin_amdgcn_mfma_i32_16x16x64_i8(a8, wq[7], acc0[1], 0, 0, 0); \
        acc0[2] = __builtin_amdgcn_mfma_i32_16x16x64_i8(a8, wq[11], acc0[2], 0, 0, 0); \
        __syncthreads();                                                         \
    }

    // region C: MFMA rt1 (reads BUFR rows 16-31) + proj(t) || VALU rt0 ->
    // h0(t+1) stores (BUFW rows 0-15) || stash pj
#define REGION_C(BUFR, BUFW, DO_PJ)                                              \
    {                                                                            \
        const signed char* rp = (BUFR) + rdOff + 16 * H8_STRIDE;                 \
        signed char*       wp = (BUFW) + wrOff;                                  \
        intx4 pj;                                                                \
        if (DO_PJ && wv < 8) {                                                   \
            intx4 a8p = *(const intx4*)((BUFR) + pjOff);                         \
            pj = __builtin_amdgcn_mfma_i32_16x16x64_i8(a8p, bproj, zero4, 0, 0, 0); \
        }                                                                        \
        intx4 a8 = *(const intx4*)(rp);                                          \
        acc1[0] = __builtin_amdgcn_mfma_i32_16x16x64_i8(a8, wq[0], zero4,   0, 0, 0); \
        acc1[1] = __builtin_amdgcn_mfma_i32_16x16x64_i8(a8, wq[4], zero4,   0, 0, 0); \
        acc1[2] = __builtin_amdgcn_mfma_i32_16x16x64_i8(a8, wq[8], zero4,   0, 0, 0); \
        HUPD_PAIR(acc0, 0, 0, wp)                                                \
        a8 = *(const intx4*)(rp + 64);                                           \
        acc1[0] = __builtin_amdgcn_mfma_i32_16x16x64_i8(a8, wq[1], acc1[0], 0, 0, 0); \
        acc1[1] = __builtin_amdgcn_mfma_i32_16x16x64_i8(a8, wq[5], acc1[1], 0, 0, 0); \
        acc1[2] = __builtin_amdgcn_mfma_i32_16x16x64_i8(a8, wq[9], acc1[2], 0, 0, 0); \
        HUPD_PAIR(acc0, 0, 1, wp)                                                \
        a8 = *(const intx4*)(rp + 128);                                          \
        acc1[0] = __builtin_amdgcn_mfma_i32_16x16x64_i8(a8, wq[2], acc1[0], 0, 0, 0); \
        acc1[1] = __builtin_amdgcn_mfma_i32_16x16x64_i8(a8, wq[6], acc1[1], 0, 0, 0); \
        acc1[2] = __builtin_amdgcn_mfma_i32_16x16x64_i8(a8, wq[10], acc1[2], 0, 0, 0); \
        a8 = *(const intx4*)(rp + 192);                                          \
        acc1[0] = __builtin_amdgcn_mfma_i32_16x16x64_i8(a8, wq[3], acc1[0], 0, 0, 0); \
        acc1[1] = __builtin_amdgcn_mfma_i32_16x16x64_i8(a8, wq[7], acc1[1], 0, 0, 0); \
        acc1[2] = __builtin_amdgcn_mfma_i32_16x16x64_i8(a8, wq[11], acc1[2], 0, 0, 0); \
        if (DO_PJ && wv < 8 && l15 < 2) {                                        \
            _Pragma("unroll")                                                    \
            for (int r = 0; r < 4; ++r)                                          \
                obufI[(rh * 4 + sl) * 32 + (qd * 4 + r) * 2 + l15] = pj[r];      \
        }                                                                        \
        __syncthreads();                                                         \
    }

    // ---- prologue: t=0,1 peeled ----
    REGION_A(h8a, 0, 0)        // A(0): MFMA0(0) only
    REGION_C(h8a, h8b, 0)      // C(0): MFMA1(0); h0(1)->buf1
    REGION_A(h8b, 1, 0)        // A(1): MFMA0(1); h1(1)->buf1
    REGION_C(h8b, h8a, 1)      // C(1): MFMA1(1); proj(1) stash; h0(2)->buf0

    // ---- steady state: t = 2..179, 89 parity pairs ----
#pragma unroll 1
    for (int t2 = 0; t2 < 89; ++t2) {
        REGION_A(h8a, 1, 1)    // even t: flush out[t-2]
        REGION_C(h8a, h8b, 1)
        REGION_A(h8b, 1, 1)    // odd t+1: flush out[t-1]
        REGION_C(h8b, h8a, 1)
    }

    // ---- epilogue ----
    {   // E1: VALU1(179) -> h1(180) -> buf0; flush stash(179) -> out idx 178
        signed char* wp = h8a + wrOff + 16 * H8_STRIDE;
        HUPD_PAIR(acc1, 1, 0, wp)
        HUPD_PAIR(acc1, 1, 1, wp)
        if (tid >= 512 && tid < 576) {
            int s_ = obufI[fbase] + obufI[fbase + 32]
                   + obufI[fbase + 64] + obufI[fbase + 96];
            *opW8 = __builtin_fmaf((float)s_, pscF, ob);
            opW8 += 2;
        }
        __syncthreads();
    }
    // E2: proj(180) read buf0 -> stash
    if (wv < 8) {
        intx4 a8p = *(const intx4*)(h8a + pjOff);
        intx4 pj = __builtin_amdgcn_mfma_i32_16x16x64_i8(a8p, bproj, zero4, 0, 0, 0);
        if (l15 < 2)
#pragma unroll
            for (int r = 0; r < 4; ++r)
                obufI[(rh * 4 + sl) * 32 + (qd * 4 + r) * 2 + l15] = pj[r];
    }
    __syncthreads();
    // E3: flush -> out idx 179
    if (tid >= 512 && tid < 576) {
        int s_ = obufI[fbase] + obufI[fbase + 32]
               + obufI[fbase + 64] + obufI[fbase + 96];
        *opW8 = __builtin_fmaf((float)s_, pscF, ob);
    }
#undef REGION_C
#undef REGION_A
#undef HUPD_PAIR
}

extern "C" void kernel_launch(void* const* d_in, const int* in_sizes, int n_in,
                              void* d_out, int out_size, void* d_ws, size_t ws_size,
                              hipStream_t stream) {
    const float* z     = (const float*)d_in[0];
    const float* fc_w  = (const float*)d_in[1];
    const float* fc_b  = (const float*)d_in[2];
    // d_in[3] = w_ih : unused (GRU input is all-zeros, gi = b_ih)
    const float* b_ih  = (const float*)d_in[4];
    const float* w_hh  = (const float*)d_in[5];
    const float* b_hh  = (const float*)d_in[6];
    const float* out_w = (const float*)d_in[7];
    const float* out_b = (const float*)d_in[8];
    float* out = (float*)d_out;
    unsigned char* ws = (unsigned char*)d_ws;   // needs 269,320 B

    hipFuncSetAttribute((const void*)gru_main,
                        hipFuncAttributeMaxDynamicSharedMemorySize, SMEM_BYTES);

    pack_scales<<<192, 256, 0, stream>>>(w_hh, (float*)(ws + SCW_OFF));
    pack_whh_i8<<<48, 256, 0, stream>>>(w_hh, (const float*)(ws + SCW_OFF),
                                        (signed char*)(ws + WQ_OFF));
    pack_fcw<<<16, 256, 0, stream>>>(fc_w, (unsigned short*)(ws + FCW_OFF));
    pack_outw_i8<<<1, 256, 0, stream>>>(out_w, (signed char*)(ws + OUTW_OFF),
                                        (float*)(ws + SWOUT_OFF));
    gru_main<<<256, 1024, SMEM_BYTES, stream>>>(z, fc_b, b_ih, b_hh, out_b, ws, out);
}